// Round 1
// baseline (634.646 us; speedup 1.0000x reference)
//
#include <hip/hip_runtime.h>
#include <math.h>

// GCN 2-layer: x(N,132) @ W1(132,16) -> edge agg -> relu -> @ W2(16,10) -> edge agg -> log_softmax
// N = 100000, E = 3200000. All fp32. edge_index delivered as int32 per harness convention.

#define F_IN 132
#define F1   16
#define F2   10

// ---- degree: indeg via atomics (self loop folded analytically later) ----
__global__ void k_degree(const int* __restrict__ dst, int E, float* __restrict__ deg) {
    int i = blockIdx.x * blockDim.x + threadIdx.x;
    if (i < E) atomicAdd(&deg[dst[i]], 1.0f);
}

__global__ void k_dinv(float* __restrict__ deg, int N) {
    int i = blockIdx.x * blockDim.x + threadIdx.x;
    if (i < N) deg[i] = 1.0f / sqrtf(deg[i] + 1.0f);   // deg includes self loop
}

// ---- h1 = x @ W1, 16 rows per 256-thread block, both tiles in LDS ----
__global__ void k_xw1(const float* __restrict__ x, const float* __restrict__ W1,
                      float* __restrict__ h1, int N) {
    __shared__ float xs[16 * F_IN];   // 2112 floats
    __shared__ float wsm[F_IN * F1];  // 2112 floats
    const int base = blockIdx.x * 16;
    for (int idx = threadIdx.x; idx < F_IN * F1; idx += 256) wsm[idx] = W1[idx];
    int nrows = N - base; if (nrows > 16) nrows = 16;
    const float* xp = x + (size_t)base * F_IN;
    const int span = nrows * F_IN;
    for (int idx = threadIdx.x; idx < span; idx += 256) xs[idx] = xp[idx];
    __syncthreads();
    const int r = threadIdx.x >> 4;
    const int c = threadIdx.x & 15;
    if (r < nrows) {
        float acc = 0.f;
        #pragma unroll 4
        for (int k = 0; k < F_IN; ++k) acc += xs[r * F_IN + k] * wsm[k * F1 + c];
        h1[(size_t)(base + r) * F1 + c] = acc;
    }
}

// ---- conv1 edge pass: one thread per (edge, feature j in 0..15) ----
__global__ void k_edge1(const int* __restrict__ src, const int* __restrict__ dst,
                        const float* __restrict__ dinv, const float* __restrict__ h1,
                        float* __restrict__ agg1, int E) {
    int tid = blockIdx.x * blockDim.x + threadIdx.x;
    int e = tid >> 4;
    if (e < E) {
        int j = tid & 15;
        int s = src[e];
        int d = dst[e];
        float w = dinv[s] * dinv[d];
        atomicAdd(&agg1[(size_t)d * F1 + j], h1[(size_t)s * F1 + j] * w);
    }
}

// ---- h2 = relu(agg1 + h1*dinv^2 + b1) @ W2 ----
__global__ void k_h2(const float* __restrict__ agg1, const float* __restrict__ h1,
                     const float* __restrict__ dinv, const float* __restrict__ b1,
                     const float* __restrict__ W2, float* __restrict__ h2, int N) {
    __shared__ float w2s[F1 * F2];  // 160
    __shared__ float b1s[F1];
    if (threadIdx.x < F1 * F2) w2s[threadIdx.x] = W2[threadIdx.x];
    if (threadIdx.x < F1) b1s[threadIdx.x] = b1[threadIdx.x];
    __syncthreads();
    int i = blockIdx.x * blockDim.x + threadIdx.x;
    if (i >= N) return;
    float dv = dinv[i];
    float dv2 = dv * dv;
    float t[F1];
    const float* ag = agg1 + (size_t)i * F1;
    const float* hp = h1 + (size_t)i * F1;
    #pragma unroll
    for (int j = 0; j < F1; ++j) {
        float v = ag[j] + hp[j] * dv2 + b1s[j];
        t[j] = v > 0.f ? v : 0.f;
    }
    float* op = h2 + (size_t)i * F2;
    #pragma unroll
    for (int c = 0; c < F2; ++c) {
        float acc = 0.f;
        #pragma unroll
        for (int j = 0; j < F1; ++j) acc += t[j] * w2s[j * F2 + c];
        op[c] = acc;
    }
}

// ---- conv2 edge pass: one thread per (edge, feature j in 0..9) ----
__global__ void k_edge2(const int* __restrict__ src, const int* __restrict__ dst,
                        const float* __restrict__ dinv, const float* __restrict__ h2,
                        float* __restrict__ agg2, int E) {
    int tid = blockIdx.x * blockDim.x + threadIdx.x;
    int e = tid / 10;
    if (e < E) {
        int j = tid - e * 10;
        int s = src[e];
        int d = dst[e];
        float w = dinv[s] * dinv[d];
        atomicAdd(&agg2[(size_t)d * F2 + j], h2[(size_t)s * F2 + j] * w);
    }
}

// ---- final: self loop + b2 + log_softmax, writes d_out in place ----
__global__ void k_final(const float* __restrict__ agg2, const float* __restrict__ h2,
                        const float* __restrict__ dinv, const float* __restrict__ b2,
                        float* __restrict__ out, int N) {
    int i = blockIdx.x * blockDim.x + threadIdx.x;
    if (i >= N) return;
    float dv = dinv[i];
    float dv2 = dv * dv;
    float v[F2];
    float m = -INFINITY;
    #pragma unroll
    for (int c = 0; c < F2; ++c) {
        v[c] = agg2[(size_t)i * F2 + c] + h2[(size_t)i * F2 + c] * dv2 + b2[c];
        m = fmaxf(m, v[c]);
    }
    float ssum = 0.f;
    #pragma unroll
    for (int c = 0; c < F2; ++c) ssum += expf(v[c] - m);
    float ls = logf(ssum);
    #pragma unroll
    for (int c = 0; c < F2; ++c) out[(size_t)i * F2 + c] = v[c] - m - ls;
}

extern "C" void kernel_launch(void* const* d_in, const int* in_sizes, int n_in,
                              void* d_out, int out_size, void* d_ws, size_t ws_size,
                              hipStream_t stream) {
    const float* x  = (const float*)d_in[0];
    const int*   ei = (const int*)  d_in[1];
    const float* W1 = (const float*)d_in[2];
    const float* b1 = (const float*)d_in[3];
    const float* W2 = (const float*)d_in[4];
    const float* b2 = (const float*)d_in[5];
    float* out = (float*)d_out;

    const int N = in_sizes[0] / F_IN;   // 100000
    const int E = in_sizes[1] / 2;      // 3200000
    const int* src = ei;
    const int* dst = ei + E;

    // Workspace layout (floats): [deg N][agg1 16N][agg2 10N][h1 16N]  = 43N ≈ 17.2 MB
    float* ws   = (float*)d_ws;
    float* deg  = ws;                       // N (becomes dinv in place)
    float* agg1 = deg  + (size_t)N;         // 16N
    float* agg2 = agg1 + (size_t)16 * N;    // 10N
    float* h1   = agg2 + (size_t)10 * N;    // 16N
    float* h2   = out;                      // reuse d_out as h2 buffer (overwritten by k_final)

    // Zero deg + agg1 + agg2 (contiguous 27N floats) — needed every launch (atomics accumulate)
    hipMemsetAsync(ws, 0, (size_t)(1 + F1 + F2) * N * sizeof(float), stream);

    k_degree<<<(E + 255) / 256, 256, 0, stream>>>(dst, E, deg);
    k_xw1<<<(N + 15) / 16, 256, 0, stream>>>(x, W1, h1, N);
    k_dinv<<<(N + 255) / 256, 256, 0, stream>>>(deg, N);

    long long t1 = (long long)E * F1;
    k_edge1<<<(unsigned)((t1 + 255) / 256), 256, 0, stream>>>(src, dst, deg, h1, agg1, E);

    k_h2<<<(N + 255) / 256, 256, 0, stream>>>(agg1, h1, deg, b1, W2, h2, N);

    long long t2 = (long long)E * F2;
    k_edge2<<<(unsigned)((t2 + 255) / 256), 256, 0, stream>>>(src, dst, deg, h2, agg2, E);

    k_final<<<(N + 255) / 256, 256, 0, stream>>>(agg2, h2, deg, b2, out, N);
}

// Round 2
// 572.711 us; speedup vs baseline: 1.1081x; 1.1081x over previous
//
#include <hip/hip_runtime.h>
#include <math.h>

// 2-layer GCN via CSR gather-aggregation (no float atomics).
// N=100000, E=3200000. fp32. edge_index as int32 (harness converts).

#define F_IN 132
#define F1   16
#define F2   10
#define F2P  16   // g2 rows padded to 16 floats (64B cachelines)

// ---- histogram of dst (in-degree, excl self loop) ----
__global__ void k_hist(const int* __restrict__ dst, int E, int* __restrict__ cnt) {
    int i = blockIdx.x * blockDim.x + threadIdx.x;
    if (i < E) atomicAdd(&cnt[dst[i]], 1);
}

// ---- dinv = rsqrt(deg+1)  (self loop) ----
__global__ void k_dinv(const int* __restrict__ cnt, float* __restrict__ dinv, int N) {
    int i = blockIdx.x * blockDim.x + threadIdx.x;
    if (i < N) dinv[i] = rsqrtf((float)cnt[i] + 1.0f);
}

// ---- g1 = (x @ W1) * dinv[row]  (pre-scaled messages) ----
__global__ void k_xw1(const float* __restrict__ x, const float* __restrict__ W1,
                      const float* __restrict__ dinv, float* __restrict__ g1, int N) {
    __shared__ float xs[16 * F_IN];
    __shared__ float wsm[F_IN * F1];
    const int base = blockIdx.x * 16;
    for (int idx = threadIdx.x; idx < F_IN * F1; idx += 256) wsm[idx] = W1[idx];
    int nrows = N - base; if (nrows > 16) nrows = 16;
    const float* xp = x + (size_t)base * F_IN;
    const int span = nrows * F_IN;
    for (int idx = threadIdx.x; idx < span; idx += 256) xs[idx] = xp[idx];
    __syncthreads();
    const int r = threadIdx.x >> 4;
    const int c = threadIdx.x & 15;
    if (r < nrows) {
        float acc = 0.f;
        #pragma unroll 4
        for (int k = 0; k < F_IN; ++k) acc += xs[r * F_IN + k] * wsm[k * F1 + c];
        g1[(size_t)(base + r) * F1 + c] = acc * dinv[base + r];
    }
}

// ---- scan stage 1: per-1024-block exclusive scan of cnt -> rp locals + block sums ----
__global__ void k_scan1(const int* __restrict__ cnt, int* __restrict__ rp,
                        int* __restrict__ bsum, int N) {
    __shared__ int sd[256];
    const int t = threadIdx.x;
    const int base = blockIdx.x * 1024 + t * 4;
    int v0 = 0, v1 = 0, v2 = 0, v3 = 0;
    if (base + 0 < N) v0 = cnt[base + 0];
    if (base + 1 < N) v1 = cnt[base + 1];
    if (base + 2 < N) v2 = cnt[base + 2];
    if (base + 3 < N) v3 = cnt[base + 3];
    int s = v0 + v1 + v2 + v3;
    sd[t] = s;
    __syncthreads();
    for (int off = 1; off < 256; off <<= 1) {
        int xx = (t >= off) ? sd[t - off] : 0;
        __syncthreads();
        sd[t] += xx;
        __syncthreads();
    }
    int run = sd[t] - s;  // exclusive prefix of this thread's chunk
    if (base + 0 < N) { rp[base + 0] = run; run += v0; }
    if (base + 1 < N) { rp[base + 1] = run; run += v1; }
    if (base + 2 < N) { rp[base + 2] = run; run += v2; }
    if (base + 3 < N) { rp[base + 3] = run; }
    if (t == 255) bsum[blockIdx.x] = sd[255];
}

// ---- scan stage 2: exclusive scan of block sums (single block) ----
__global__ void k_scan2(int* __restrict__ bsum, int nb) {
    __shared__ int sd[128];
    const int t = threadIdx.x;
    int v = (t < nb) ? bsum[t] : 0;
    sd[t] = v;
    __syncthreads();
    for (int off = 1; off < 128; off <<= 1) {
        int xx = (t >= off) ? sd[t - off] : 0;
        __syncthreads();
        sd[t] += xx;
        __syncthreads();
    }
    if (t < nb) bsum[t] = sd[t] - v;
}

// ---- scan stage 3: add block offsets; produce rowptr + cursor copy; rowptr[N]=E ----
__global__ void k_scan3(int* __restrict__ rp, const int* __restrict__ bsum,
                        int* __restrict__ cursor, int N, int E) {
    int i = blockIdx.x * blockDim.x + threadIdx.x;
    if (i < N) {
        int r = rp[i] + bsum[i >> 10];
        rp[i] = r;
        cursor[i] = r;
    } else if (i == N) {
        rp[N] = E;
    }
}

// ---- counting-sort scatter: bucket src by dst ----
__global__ void k_scatter(const int* __restrict__ src, const int* __restrict__ dst,
                          int* __restrict__ cursor, int* __restrict__ ssrc, int E) {
    int i = blockIdx.x * blockDim.x + threadIdx.x;
    if (i < E) {
        int d = dst[i];
        int pos = atomicAdd(&cursor[d], 1);
        ssrc[pos] = src[i];
    }
}

// ---- layer-1 aggregation fused with relu, @W2, dinv pre-scale -> g2 (padded 16) ----
__global__ void k_agg1(const int* __restrict__ rp, const int* __restrict__ ssrc,
                       const float* __restrict__ g1, const float* __restrict__ dinv,
                       const float* __restrict__ b1, const float* __restrict__ W2,
                       float* __restrict__ g2, int N) {
    __shared__ float w2s[F1 * F2];
    __shared__ float b1s[F1];
    if (threadIdx.x < F1 * F2) w2s[threadIdx.x] = W2[threadIdx.x];
    if (threadIdx.x < F1) b1s[threadIdx.x] = b1[threadIdx.x];
    __syncthreads();
    int d = blockIdx.x * blockDim.x + threadIdx.x;
    if (d >= N) return;
    const int beg = rp[d], end = rp[d + 1];
    float acc[F1];
    #pragma unroll
    for (int j = 0; j < F1; ++j) acc[j] = 0.f;
    for (int e = beg; e < end; ++e) {
        int s = ssrc[e];
        const float4* r = (const float4*)(g1 + (size_t)s * F1);
        float4 v0 = r[0], v1 = r[1], v2 = r[2], v3 = r[3];
        acc[0] += v0.x; acc[1] += v0.y; acc[2]  += v0.z; acc[3]  += v0.w;
        acc[4] += v1.x; acc[5] += v1.y; acc[6]  += v1.z; acc[7]  += v1.w;
        acc[8] += v2.x; acc[9] += v2.y; acc[10] += v2.z; acc[11] += v2.w;
        acc[12] += v3.x; acc[13] += v3.y; acc[14] += v3.z; acc[15] += v3.w;
    }
    // self loop
    {
        const float4* r = (const float4*)(g1 + (size_t)d * F1);
        float4 v0 = r[0], v1 = r[1], v2 = r[2], v3 = r[3];
        acc[0] += v0.x; acc[1] += v0.y; acc[2]  += v0.z; acc[3]  += v0.w;
        acc[4] += v1.x; acc[5] += v1.y; acc[6]  += v1.z; acc[7]  += v1.w;
        acc[8] += v2.x; acc[9] += v2.y; acc[10] += v2.z; acc[11] += v2.w;
        acc[12] += v3.x; acc[13] += v3.y; acc[14] += v3.z; acc[15] += v3.w;
    }
    const float dv = dinv[d];
    float t[F1];
    #pragma unroll
    for (int j = 0; j < F1; ++j) {
        float v = dv * acc[j] + b1s[j];
        t[j] = v > 0.f ? v : 0.f;
    }
    float o[F2P];
    #pragma unroll
    for (int c = 0; c < F2; ++c) {
        float a = 0.f;
        #pragma unroll
        for (int j = 0; j < F1; ++j) a += t[j] * w2s[j * F2 + c];
        o[c] = dv * a;   // pre-scale layer-2 message by dinv[d]
    }
    #pragma unroll
    for (int c = F2; c < F2P; ++c) o[c] = 0.f;
    float4* op = (float4*)(g2 + (size_t)d * F2P);
    op[0] = make_float4(o[0], o[1], o[2], o[3]);
    op[1] = make_float4(o[4], o[5], o[6], o[7]);
    op[2] = make_float4(o[8], o[9], o[10], o[11]);
    op[3] = make_float4(o[12], o[13], o[14], o[15]);
}

// ---- layer-2 aggregation fused with bias + log_softmax -> out ----
__global__ void k_agg2(const int* __restrict__ rp, const int* __restrict__ ssrc,
                       const float* __restrict__ g2, const float* __restrict__ dinv,
                       const float* __restrict__ b2, float* __restrict__ out, int N) {
    __shared__ float b2s[F2];
    if (threadIdx.x < F2) b2s[threadIdx.x] = b2[threadIdx.x];
    __syncthreads();
    int d = blockIdx.x * blockDim.x + threadIdx.x;
    if (d >= N) return;
    const int beg = rp[d], end = rp[d + 1];
    float acc[F2];
    #pragma unroll
    for (int c = 0; c < F2; ++c) acc[c] = 0.f;
    for (int e = beg; e < end; ++e) {
        int s = ssrc[e];
        const float* r = g2 + (size_t)s * F2P;
        float4 v0 = *(const float4*)(r);
        float4 v1 = *(const float4*)(r + 4);
        float2 v2 = *(const float2*)(r + 8);
        acc[0] += v0.x; acc[1] += v0.y; acc[2] += v0.z; acc[3] += v0.w;
        acc[4] += v1.x; acc[5] += v1.y; acc[6] += v1.z; acc[7] += v1.w;
        acc[8] += v2.x; acc[9] += v2.y;
    }
    {   // self loop
        const float* r = g2 + (size_t)d * F2P;
        float4 v0 = *(const float4*)(r);
        float4 v1 = *(const float4*)(r + 4);
        float2 v2 = *(const float2*)(r + 8);
        acc[0] += v0.x; acc[1] += v0.y; acc[2] += v0.z; acc[3] += v0.w;
        acc[4] += v1.x; acc[5] += v1.y; acc[6] += v1.z; acc[7] += v1.w;
        acc[8] += v2.x; acc[9] += v2.y;
    }
    const float dv = dinv[d];
    float v[F2];
    float m = -INFINITY;
    #pragma unroll
    for (int c = 0; c < F2; ++c) {
        v[c] = dv * acc[c] + b2s[c];
        m = fmaxf(m, v[c]);
    }
    float ssum = 0.f;
    #pragma unroll
    for (int c = 0; c < F2; ++c) ssum += expf(v[c] - m);
    float ls = logf(ssum);
    float* op = out + (size_t)d * F2;
    #pragma unroll
    for (int c = 0; c < F2; ++c) op[c] = v[c] - m - ls;
}

extern "C" void kernel_launch(void* const* d_in, const int* in_sizes, int n_in,
                              void* d_out, int out_size, void* d_ws, size_t ws_size,
                              hipStream_t stream) {
    const float* x  = (const float*)d_in[0];
    const int*   ei = (const int*)  d_in[1];
    const float* W1 = (const float*)d_in[2];
    const float* b1 = (const float*)d_in[3];
    const float* W2 = (const float*)d_in[4];
    const float* b2 = (const float*)d_in[5];
    float* out = (float*)d_out;

    const int N = in_sizes[0] / F_IN;   // 100000
    const int E = in_sizes[1] / 2;      // 3200000
    const int* src = ei;
    const int* dst = ei + E;
    const int nb = (N + 1023) / 1024;   // scan blocks (98)

    // ---- workspace layout ----
    char* w = (char*)d_ws;
    int*   cnt    = (int*)w;                 w += (size_t)N * 4;        // also reused as cursor
    int*   rp     = (int*)w;                 w += (size_t)(N + 1) * 4;
    int*   bsum   = (int*)w;                 w += 128 * 4;
    int*   ssrc   = (int*)w;                 w += (size_t)E * 4;
    float* dinv   = (float*)w;               w += (size_t)N * 4;
    float* g1     = (float*)w;               w += (size_t)N * F1 * 4;
    float* g2     = (float*)w;               /* N * F2P * 4 */
    int* cursor = cnt;  // cnt dead after scan1/dinv; reuse as scatter cursor

    hipMemsetAsync(cnt, 0, (size_t)N * 4, stream);

    k_hist<<<(E + 255) / 256, 256, 0, stream>>>(dst, E, cnt);
    k_dinv<<<(N + 255) / 256, 256, 0, stream>>>(cnt, dinv, N);
    k_xw1 <<<(N + 15) / 16, 256, 0, stream>>>(x, W1, dinv, g1, N);

    k_scan1<<<nb, 256, 0, stream>>>(cnt, rp, bsum, N);
    k_scan2<<<1, 128, 0, stream>>>(bsum, nb);
    k_scan3<<<(N + 256) / 256, 256, 0, stream>>>(rp, bsum, cursor, N, E);

    k_scatter<<<(E + 255) / 256, 256, 0, stream>>>(src, dst, cursor, ssrc, E);

    k_agg1<<<(N + 255) / 256, 256, 0, stream>>>(rp, ssrc, g1, dinv, b1, W2, g2, N);
    k_agg2<<<(N + 255) / 256, 256, 0, stream>>>(rp, ssrc, g2, dinv, b2, out, N);
}